// Round 1
// baseline (265.855 us; speedup 1.0000x reference)
//
#include <hip/hip_runtime.h>

#define BB 32
#define MM 512
#define NN 4096
#define KK 4
#define IOU_T 0.6f

__device__ __forceinline__ bool beats(float v1, int i1, float v2, int i2) {
    // total order: value descending, index ascending (JAX top_k tie-break)
    return (v1 > v2) || (v1 == v2 && i1 < i2);
}

#define CE(av, ai, bv, bi) \
    { if (beats(bv, bi, av, ai)) { float _tv = av; av = bv; bv = _tv; int _ti = ai; ai = bi; bi = _ti; } }

// Kernel A: per-gt top-4 over proposals + max_per_gt; zero counts.
// One wave (64 lanes) per gt row; 4 gt rows per 256-thread block.
__global__ __launch_bounds__(256) void kernA(const float* __restrict__ gt,
                                             const float* __restrict__ pr,
                                             float* __restrict__ maxpg,
                                             float* __restrict__ topv,
                                             int* __restrict__ topi,
                                             int* __restrict__ counts) {
    __shared__ float px1[NN], py1[NN], px2[NN], py2[NN];
    const int b = blockIdx.x >> 7;          // 128 blocks per batch (512/4)
    const int mblk = blockIdx.x & 127;
    const int tid = threadIdx.x;

    const float4* p4 = (const float4*)(pr + (size_t)b * NN * 4);
    for (int n = tid; n < NN; n += 256) {
        float4 q = p4[n];
        px1[n] = q.x - 0.5f * q.z;
        py1[n] = q.y - 0.5f * q.w;
        px2[n] = q.x + 0.5f * q.z;
        py2[n] = q.y + 0.5f * q.w;
    }
    __syncthreads();

    const int wave = tid >> 6, lane = tid & 63;
    const int m = mblk * 4 + wave;
    float4 g = ((const float4*)(gt + (size_t)b * MM * 4))[m];
    const float gx1 = g.x - 0.5f * g.z, gy1 = g.y - 0.5f * g.w;
    const float gx2 = g.x + 0.5f * g.z, gy2 = g.y + 0.5f * g.w;
    const float ga = (gx2 - gx1) * (gy2 - gy1);

    float v0 = -1e30f, v1 = -1e30f, v2 = -1e30f, v3 = -1e30f;
    int i0 = 0x7fffffff, i1 = 0x7fffffff, i2 = 0x7fffffff, i3 = 0x7fffffff;

    for (int j = 0; j < NN / 64; ++j) {
        const int n = j * 64 + lane;           // ascending per lane -> tie-break safe
        float qx1 = px1[n], qy1 = py1[n], qx2 = px2[n], qy2 = py2[n];
        float pa = (qx2 - qx1) * (qy2 - qy1);
        float ltx = fmaxf(gx1, qx1), lty = fmaxf(gy1, qy1);
        float rbx = fminf(gx2, qx2), rby = fminf(gy2, qy2);
        float w = fmaxf(rbx - ltx, 0.0f), h = fmaxf(rby - lty, 0.0f);
        float inter = w * h;
        float uni = ga + pa - inter;
        float iou = inter / fmaxf(uni, 1e-9f);
        if (beats(iou, n, v3, i3)) {
            if (beats(iou, n, v2, i2)) {
                v3 = v2; i3 = i2;
                if (beats(iou, n, v1, i1)) {
                    v2 = v1; i2 = i1;
                    if (beats(iou, n, v0, i0)) { v1 = v0; i1 = i0; v0 = iou; i0 = n; }
                    else                       { v1 = iou; i1 = n; }
                } else { v2 = iou; i2 = n; }
            } else { v3 = iou; i3 = n; }
        }
    }

    // Wave butterfly: merge two sorted-4 lists (bitonic, static indexing only).
    for (int off = 1; off < 64; off <<= 1) {
        float b0 = __shfl_xor(v0, off), b1 = __shfl_xor(v1, off);
        float b2 = __shfl_xor(v2, off), b3 = __shfl_xor(v3, off);
        int j0 = __shfl_xor(i0, off), j1 = __shfl_xor(i1, off);
        int j2 = __shfl_xor(i2, off), j3 = __shfl_xor(i3, off);
        // x = [v0,v1,v2,v3, b3,b2,b1,b0] is bitonic (desc then asc)
        float x0 = v0, x1 = v1, x2 = v2, x3 = v3, x4 = b3, x5 = b2, x6 = b1, x7 = b0;
        int   y0 = i0, y1 = i1, y2 = i2, y3 = i3, y4 = j3, y5 = j2, y6 = j1, y7 = j0;
        CE(x0, y0, x4, y4); CE(x1, y1, x5, y5); CE(x2, y2, x6, y6); CE(x3, y3, x7, y7);
        // low half now holds top-4 and is bitonic; sort it
        CE(x0, y0, x2, y2); CE(x1, y1, x3, y3);
        CE(x0, y0, x1, y1); CE(x2, y2, x3, y3);
        v0 = x0; v1 = x1; v2 = x2; v3 = x3;
        i0 = y0; i1 = y1; i2 = y2; i3 = y3;
    }

    if (lane == 0) {
        const int gm = b * MM + m;
        maxpg[gm] = v0;
        topv[gm * KK + 0] = v0; topv[gm * KK + 1] = v1;
        topv[gm * KK + 2] = v2; topv[gm * KK + 3] = v3;
        topi[gm * KK + 0] = i0; topi[gm * KK + 1] = i1;
        topi[gm * KK + 2] = i2; topi[gm * KK + 3] = i3;
        counts[gm] = 0;
    }
}

// Kernel B: per-proposal argmax over gts, fg/lq, scatter-add counts.
__global__ __launch_bounds__(256) void kernB(const float* __restrict__ gt,
                                             const float* __restrict__ pr,
                                             const float* __restrict__ maxpg,
                                             int* __restrict__ counts) {
    __shared__ float gx1[MM], gy1[MM], gx2[MM], gy2[MM], gar[MM], gmx[MM];
    const int b = blockIdx.x >> 4;          // 16 blocks per batch (4096/256)
    const int nblk = blockIdx.x & 15;
    const int tid = threadIdx.x;

    for (int m = tid; m < MM; m += 256) {
        float4 g = ((const float4*)(gt + (size_t)b * MM * 4))[m];
        float a1 = g.x - 0.5f * g.z, b1 = g.y - 0.5f * g.w;
        float c1 = g.x + 0.5f * g.z, d1 = g.y + 0.5f * g.w;
        gx1[m] = a1; gy1[m] = b1; gx2[m] = c1; gy2[m] = d1;
        gar[m] = (c1 - a1) * (d1 - b1);
        gmx[m] = maxpg[b * MM + m];
    }
    __syncthreads();

    const int n = nblk * 256 + tid;
    float4 q = ((const float4*)(pr + (size_t)b * NN * 4))[n];
    const float qx1 = q.x - 0.5f * q.z, qy1 = q.y - 0.5f * q.w;
    const float qx2 = q.x + 0.5f * q.z, qy2 = q.y + 0.5f * q.w;
    const float pa = (qx2 - qx1) * (qy2 - qy1);

    float best = -1e30f;
    int bidx = 0;
    bool lq = false;
    for (int m = 0; m < MM; ++m) {
        float ltx = fmaxf(gx1[m], qx1), lty = fmaxf(gy1[m], qy1);
        float rbx = fminf(gx2[m], qx2), rby = fminf(gy2[m], qy2);
        float w = fmaxf(rbx - ltx, 0.0f), h = fmaxf(rby - lty, 0.0f);
        float inter = w * h;
        float uni = gar[m] + pa - inter;
        float iou = inter / fmaxf(uni, 1e-9f);
        if (iou > best) { best = iou; bidx = m; }   // first max kept, like jnp.argmax
        lq = lq || (iou == gmx[m]);
    }
    if (best >= IOU_T || lq) {
        atomicAdd(&counts[b * MM + bidx], 1);
    }
}

// Kernel C: write the 4 concatenated float32 output sections.
__global__ __launch_bounds__(256) void kernC(const float* __restrict__ topv,
                                             const int* __restrict__ topi,
                                             const int* __restrict__ counts,
                                             float* __restrict__ out) {
    const int gm = blockIdx.x * 256 + threadIdx.x;   // 0 .. B*M-1
    if (gm >= BB * MM) return;
    const int cnt = counts[gm];
    const int m = gm & (MM - 1);
    float* sc = out;
    float* pi = out + (size_t)BB * MM * KK;
    float* gi = out + (size_t)2 * BB * MM * KK;
    float* va = out + (size_t)3 * BB * MM * KK;
    #pragma unroll
    for (int k = 0; k < KK; ++k) {
        const bool val = k < cnt;
        sc[gm * KK + k] = val ? topv[gm * KK + k] : 0.0f;
        pi[gm * KK + k] = (float)topi[gm * KK + k];
        gi[gm * KK + k] = (float)m;
        va[gm * KK + k] = val ? 1.0f : 0.0f;
    }
}

extern "C" void kernel_launch(void* const* d_in, const int* in_sizes, int n_in,
                              void* d_out, int out_size, void* d_ws, size_t ws_size,
                              hipStream_t stream) {
    const float* gt = (const float*)d_in[0];   // [B,M,4] cxcywh
    const float* pr = (const float*)d_in[1];   // [B,N,4] cxcywh
    // d_in[2] (gt_labels) is unused by the reference outputs.
    float* out = (float*)d_out;
    char* ws = (char*)d_ws;

    int*   counts = (int*)(ws);                 //  64 KB
    float* maxpg  = (float*)(ws + (1 << 16));   //  64 KB
    float* topv   = (float*)(ws + (2 << 16));   // 256 KB
    int*   topi   = (int*)(ws + (6 << 16));     // 256 KB

    kernA<<<BB * (MM / 4), 256, 0, stream>>>(gt, pr, maxpg, topv, topi, counts);
    kernB<<<BB * (NN / 256), 256, 0, stream>>>(gt, pr, maxpg, counts);
    kernC<<<(BB * MM + 255) / 256, 256, 0, stream>>>(topv, topi, counts, out);
}

// Round 2
// 155.573 us; speedup vs baseline: 1.7089x; 1.7089x over previous
//
#include <hip/hip_runtime.h>

#define BB 32
#define MM 512
#define NN 4096
#define KK 4
#define IOU_T 0.6f

__device__ __forceinline__ bool beats(float v1, int i1, float v2, int i2) {
    // total order: value descending, index ascending (JAX top_k tie-break)
    return (v1 > v2) || (v1 == v2 && i1 < i2);
}

// branchless compare-exchange keeping the winner in (av,ai)
#define CE(av, ai, bv, bi)                                         \
    {                                                              \
        bool _s = beats(bv, bi, av, ai);                           \
        float _mv = _s ? bv : av, _nv = _s ? av : bv;              \
        int   _mi = _s ? bi : ai, _ni = _s ? ai : bi;              \
        av = _mv; bv = _nv; ai = _mi; bi = _ni;                    \
    }

// Kernel A: per-gt top-4 over proposals + max_per_gt; zero counts.
// One wave (64 lanes) per gt row; 8 gt rows per 512-thread block.
__global__ __launch_bounds__(512, 4) void kernA(const float* __restrict__ gt,
                                                const float* __restrict__ pr,
                                                float* __restrict__ maxpg,
                                                float* __restrict__ topv,
                                                int* __restrict__ topi,
                                                int* __restrict__ counts) {
    __shared__ float4 pbox[NN];             // xyxy, 64 KB
    const int b = blockIdx.x >> 6;          // 64 blocks per batch (512/8)
    const int mblk = blockIdx.x & 63;
    const int tid = threadIdx.x;

    const float4* p4 = (const float4*)(pr + (size_t)b * NN * 4);
    for (int n = tid; n < NN; n += 512) {
        float4 q = p4[n];
        pbox[n] = make_float4(q.x - 0.5f * q.z, q.y - 0.5f * q.w,
                              q.x + 0.5f * q.z, q.y + 0.5f * q.w);
    }
    __syncthreads();

    const int wave = tid >> 6, lane = tid & 63;
    const int m = mblk * 8 + wave;
    float4 g = ((const float4*)(gt + (size_t)b * MM * 4))[m];
    const float gx1 = g.x - 0.5f * g.z, gy1 = g.y - 0.5f * g.w;
    const float gx2 = g.x + 0.5f * g.z, gy2 = g.y + 0.5f * g.w;
    const float ga = (gx2 - gx1) * (gy2 - gy1);

    float v0 = -1e30f, v1 = -1e30f, v2 = -1e30f, v3 = -1e30f;
    int i0 = 0x7fffffff, i1 = 0x7fffffff, i2 = 0x7fffffff, i3 = 0x7fffffff;

    #pragma unroll 4
    for (int j = 0; j < NN / 64; ++j) {
        const int n = j * 64 + lane;            // ascending per lane
        float4 q = pbox[n];
        float pa = (q.z - q.x) * (q.w - q.y);
        float ltx = fmaxf(gx1, q.x), lty = fmaxf(gy1, q.y);
        float rbx = fminf(gx2, q.z), rby = fminf(gy2, q.w);
        float w = fmaxf(rbx - ltx, 0.0f), h = fmaxf(rby - lty, 0.0f);
        float inter = w * h;
        float uni = ga + pa - inter;
        float iou = inter / fmaxf(uni, 1e-9f);  // IEEE div: must match np rounding
        // branchless sorted-insert; new index n > all stored indices, so
        // tie (iou == vk) must NOT displace -> strict > is exactly right.
        bool c0 = iou > v0, c1 = iou > v1, c2 = iou > v2, c3 = iou > v3;
        v3 = c2 ? v2 : (c3 ? iou : v3);  i3 = c2 ? i2 : (c3 ? n : i3);
        v2 = c1 ? v1 : (c2 ? iou : v2);  i2 = c1 ? i1 : (c2 ? n : i2);
        v1 = c0 ? v0 : (c1 ? iou : v1);  i1 = c0 ? i0 : (c1 ? n : i1);
        v0 = c0 ? iou : v0;              i0 = c0 ? n  : i0;
    }

    // Wave butterfly: merge two sorted-4 lists (bitonic, static indexing only).
    for (int off = 1; off < 64; off <<= 1) {
        float b0 = __shfl_xor(v0, off), b1 = __shfl_xor(v1, off);
        float b2 = __shfl_xor(v2, off), b3 = __shfl_xor(v3, off);
        int j0 = __shfl_xor(i0, off), j1 = __shfl_xor(i1, off);
        int j2 = __shfl_xor(i2, off), j3 = __shfl_xor(i3, off);
        // x = [v0,v1,v2,v3, b3,b2,b1,b0] is bitonic (desc then asc)
        float x0 = v0, x1 = v1, x2 = v2, x3 = v3, x4 = b3, x5 = b2, x6 = b1, x7 = b0;
        int   y0 = i0, y1 = i1, y2 = i2, y3 = i3, y4 = j3, y5 = j2, y6 = j1, y7 = j0;
        CE(x0, y0, x4, y4); CE(x1, y1, x5, y5); CE(x2, y2, x6, y6); CE(x3, y3, x7, y7);
        // low half now holds top-4 and is bitonic; sort it
        CE(x0, y0, x2, y2); CE(x1, y1, x3, y3);
        CE(x0, y0, x1, y1); CE(x2, y2, x3, y3);
        v0 = x0; v1 = x1; v2 = x2; v3 = x3;
        i0 = y0; i1 = y1; i2 = y2; i3 = y3;
    }

    if (lane == 0) {
        const int gm = b * MM + m;
        maxpg[gm] = v0;
        topv[gm * KK + 0] = v0; topv[gm * KK + 1] = v1;
        topv[gm * KK + 2] = v2; topv[gm * KK + 3] = v3;
        topi[gm * KK + 0] = i0; topi[gm * KK + 1] = i1;
        topi[gm * KK + 2] = i2; topi[gm * KK + 3] = i3;
        counts[gm] = 0;
    }
}

// Kernel B: per-proposal argmax over gts, fg/lq, scatter-add counts.
// 128 proposals per 256-thread block; each thread reduces half the gts,
// pairs merged through LDS (halves parallelism-starved round-1 loop).
__global__ __launch_bounds__(256) void kernB(const float* __restrict__ gt,
                                             const float* __restrict__ pr,
                                             const float* __restrict__ maxpg,
                                             int* __restrict__ counts) {
    __shared__ float4 gbox[MM];             // xyxy, 8 KB
    __shared__ float gar[MM], gmx[MM];      // 4 KB
    __shared__ float sBest[256];
    __shared__ int   sIdx[256];
    __shared__ int   sLq[256];
    const int b = blockIdx.x >> 5;          // 32 blocks per batch (4096/128)
    const int nblk = blockIdx.x & 31;
    const int tid = threadIdx.x;

    for (int m = tid; m < MM; m += 256) {
        float4 g = ((const float4*)(gt + (size_t)b * MM * 4))[m];
        float x1 = g.x - 0.5f * g.z, y1 = g.y - 0.5f * g.w;
        float x2 = g.x + 0.5f * g.z, y2 = g.y + 0.5f * g.w;
        gbox[m] = make_float4(x1, y1, x2, y2);
        gar[m] = (x2 - x1) * (y2 - y1);
        gmx[m] = maxpg[b * MM + m];
    }
    __syncthreads();

    const int half = tid >> 7;              // 0 or 1
    const int p = tid & 127;
    const int n = nblk * 128 + p;
    float4 q = ((const float4*)(pr + (size_t)b * NN * 4))[n];
    const float qx1 = q.x - 0.5f * q.z, qy1 = q.y - 0.5f * q.w;
    const float qx2 = q.x + 0.5f * q.z, qy2 = q.y + 0.5f * q.w;
    const float pa = (qx2 - qx1) * (qy2 - qy1);

    float best = -1e30f;
    int bidx = 0;
    bool lq = false;
    const int m0 = half * (MM / 2);
    #pragma unroll 4
    for (int mm = 0; mm < MM / 2; ++mm) {
        const int m = m0 + mm;
        float4 gb = gbox[m];
        float ltx = fmaxf(gb.x, qx1), lty = fmaxf(gb.y, qy1);
        float rbx = fminf(gb.z, qx2), rby = fminf(gb.w, qy2);
        float w = fmaxf(rbx - ltx, 0.0f), h = fmaxf(rby - lty, 0.0f);
        float inter = w * h;
        float uni = gar[m] + pa - inter;
        float iou = inter / fmaxf(uni, 1e-9f);
        bool c = iou > best;                // first max kept, like jnp.argmax
        best = c ? iou : best;
        bidx = c ? m : bidx;
        lq = lq || (iou == gmx[m]);
    }
    sBest[tid] = best; sIdx[tid] = bidx; sLq[tid] = lq ? 1 : 0;
    __syncthreads();

    if (tid < 128) {
        float b0 = sBest[tid], b1 = sBest[tid + 128];
        int   e0 = sIdx[tid],  e1 = sIdx[tid + 128];
        bool  l  = (sLq[tid] | sLq[tid + 128]) != 0;
        bool  c  = b1 > b0;                 // tie -> half 0 (lower m) wins
        float bb = c ? b1 : b0;
        int   bi = c ? e1 : e0;
        if (bb >= IOU_T || l) {
            atomicAdd(&counts[b * MM + bi], 1);
        }
    }
}

// Kernel C: write the 4 concatenated float32 output sections.
__global__ __launch_bounds__(256) void kernC(const float* __restrict__ topv,
                                             const int* __restrict__ topi,
                                             const int* __restrict__ counts,
                                             float* __restrict__ out) {
    const int gm = blockIdx.x * 256 + threadIdx.x;   // 0 .. B*M-1
    if (gm >= BB * MM) return;
    const int cnt = counts[gm];
    const int m = gm & (MM - 1);
    float* sc = out;
    float* pi = out + (size_t)BB * MM * KK;
    float* gi = out + (size_t)2 * BB * MM * KK;
    float* va = out + (size_t)3 * BB * MM * KK;
    #pragma unroll
    for (int k = 0; k < KK; ++k) {
        const bool val = k < cnt;
        sc[gm * KK + k] = val ? topv[gm * KK + k] : 0.0f;
        pi[gm * KK + k] = (float)topi[gm * KK + k];
        gi[gm * KK + k] = (float)m;
        va[gm * KK + k] = val ? 1.0f : 0.0f;
    }
}

extern "C" void kernel_launch(void* const* d_in, const int* in_sizes, int n_in,
                              void* d_out, int out_size, void* d_ws, size_t ws_size,
                              hipStream_t stream) {
    const float* gt = (const float*)d_in[0];   // [B,M,4] cxcywh
    const float* pr = (const float*)d_in[1];   // [B,N,4] cxcywh
    // d_in[2] (gt_labels) is unused by the reference outputs.
    float* out = (float*)d_out;
    char* ws = (char*)d_ws;

    int*   counts = (int*)(ws);                 //  64 KB
    float* maxpg  = (float*)(ws + (1 << 16));   //  64 KB
    float* topv   = (float*)(ws + (2 << 16));   // 256 KB
    int*   topi   = (int*)(ws + (6 << 16));     // 256 KB

    kernA<<<BB * (MM / 8), 512, 0, stream>>>(gt, pr, maxpg, topv, topi, counts);
    kernB<<<BB * (NN / 128), 256, 0, stream>>>(gt, pr, maxpg, counts);
    kernC<<<(BB * MM + 255) / 256, 256, 0, stream>>>(topv, topi, counts, out);
}